// Round 3
// baseline (264.669 us; speedup 1.0000x reference)
//
#include <hip/hip_runtime.h>

// Problem constants (fixed by the reference).
#define BS 64
#define DX 512
#define DY 512
#define L (DX * DY)                 // 262144 bins per sample
#define TILE 4096                   // elements per tile
#define T_PER_S (L / TILE)          // 64 tiles per sample
#define THREADS 256
#define EPT (TILE / THREADS)        // 16 elements per thread

typedef float vfloat2 __attribute__((ext_vector_type(2)));

// ---------------------------------------------------------------------------
// Phase 1: per-tile nonzero counts. Fully coalesced: lane-consecutive float4
// loads (ordering is irrelevant for counting).
// ---------------------------------------------------------------------------
__global__ __launch_bounds__(THREADS) void htpc_count(
    const float* __restrict__ hist, int* __restrict__ tile_count) {
  const int tile = blockIdx.x;
  const float4* h4 = (const float4*)(hist + (size_t)tile * TILE);

  int cnt = 0;
#pragma unroll
  for (int r = 0; r < EPT / 4; ++r) {
    float4 v = h4[r * THREADS + threadIdx.x];
    cnt += (v.x != 0.f) + (v.y != 0.f) + (v.z != 0.f) + (v.w != 0.f);
  }
  const int lane = threadIdx.x & 63;
  const int wv = threadIdx.x >> 6;
#pragma unroll
  for (int d = 32; d > 0; d >>= 1) cnt += __shfl_down(cnt, d);
  __shared__ int ws[THREADS / 64];
  if (lane == 0) ws[wv] = cnt;
  __syncthreads();
  if (threadIdx.x == 0) {
    int s = 0;
#pragma unroll
    for (int i = 0; i < THREADS / 64; ++i) s += ws[i];
    tile_count[tile] = s;
  }
}

// ---------------------------------------------------------------------------
// Phase 2: per-sample exclusive scan over 64 tile counts (one wave per
// sample). Emits tile base offsets, lens[b] as float (output) and int (ws).
// ---------------------------------------------------------------------------
__global__ __launch_bounds__(64) void htpc_scan(
    const int* __restrict__ tile_count, int* __restrict__ tile_off,
    float* __restrict__ out_lens, int* __restrict__ lens_i) {
  const int b = blockIdx.x;
  const int t = threadIdx.x;  // 0..63
  const int c = tile_count[b * T_PER_S + t];
  int incl = c;
#pragma unroll
  for (int d = 1; d < 64; d <<= 1) {
    int n = __shfl_up(incl, d);
    if (t >= d) incl += n;
  }
  tile_off[b * T_PER_S + t] = incl - c;  // exclusive
  if (t == 63) {
    out_lens[b] = (float)incl;
    lens_i[b] = incl;
  }
}

// ---------------------------------------------------------------------------
// Phase 3: stable compaction + tail zeroing, fused.
// Each block: read its tile (per-thread contiguous 16-elem chunk => thread
// order == row-major order => stable), block-scan ranks, stage (idx, w) in
// LDS, stream out coalesced nontemporal (x,y) pairs and weights, then zero
// the output stripe [t*TILE,(t+1)*TILE) ∩ [lens[b], L).
// ---------------------------------------------------------------------------
__global__ __launch_bounds__(THREADS) void htpc_compact_tail(
    const float* __restrict__ hist, const float* __restrict__ x_lims,
    const float* __restrict__ y_lims, const int* __restrict__ tile_off,
    const int* __restrict__ lens_i, float* __restrict__ out_pc,
    float* __restrict__ out_w) {
  __shared__ int sidx[TILE];        // 16 KiB
  __shared__ float sw[TILE];        // 16 KiB
  __shared__ int wsum[THREADS / 64];

  const int tile = blockIdx.x;
  const int b = tile / T_PER_S;
  const int t = tile % T_PER_S;
  const size_t gbase = (size_t)tile * TILE + (size_t)threadIdx.x * EPT;
  const float4* h4 = (const float4*)(hist + gbase);

  float v[EPT];
#pragma unroll
  for (int i = 0; i < EPT / 4; ++i) {
    float4 a = h4[i];
    v[i * 4 + 0] = a.x;
    v[i * 4 + 1] = a.y;
    v[i * 4 + 2] = a.z;
    v[i * 4 + 3] = a.w;
  }
  int cnt = 0;
#pragma unroll
  for (int i = 0; i < EPT; ++i) cnt += (v[i] != 0.f);

  // block exclusive scan over 256 thread counts (4 waves)
  const int lane = threadIdx.x & 63;
  const int wv = threadIdx.x >> 6;
  int incl = cnt;
#pragma unroll
  for (int d = 1; d < 64; d <<= 1) {
    int n = __shfl_up(incl, d);
    if (lane >= d) incl += n;
  }
  if (lane == 63) wsum[wv] = incl;
  __syncthreads();
  int wbase = 0, total = 0;
#pragma unroll
  for (int i = 0; i < THREADS / 64; ++i) {
    int s = wsum[i];
    if (i < wv) wbase += s;
    total += s;
  }
  int r = wbase + (incl - cnt);  // stable exclusive rank within tile

  const int lidx0 = (int)(gbase - (size_t)b * L);  // index within sample
#pragma unroll
  for (int i = 0; i < EPT; ++i) {
    if (v[i] != 0.f) {
      sidx[r] = lidx0 + i;
      sw[r] = v[i];
      ++r;
    }
  }
  __syncthreads();

  // center-grid params: cx[j] = xlo + cxw*(j+0.5)
  const float xlo = x_lims[b * 2], xhi = x_lims[b * 2 + 1];
  const float ylo = y_lims[b * 2], yhi = y_lims[b * 2 + 1];
  const float cxw = (xhi - xlo) / DX;
  const float cyw = (yhi - ylo) / DY;

  const int off = tile_off[tile];
  vfloat2* pc2 = (vfloat2*)out_pc + (size_t)b * L;  // pair units
  float* w = out_w + (size_t)b * L;

  // coalesced nontemporal stream-out of the compacted run
  for (int k = threadIdx.x; k < total; k += THREADS) {
    const int idx = sidx[k];
    const int ix = idx >> 9;   // idx / DY
    const int iy = idx & 511;  // idx % DY
    vfloat2 p;
    p.x = xlo + cxw * ((float)ix + 0.5f);
    p.y = ylo + cyw * ((float)iy + 0.5f);
    __builtin_nontemporal_store(p, pc2 + (off + k));
    __builtin_nontemporal_store(sw[k], w + (off + k));
  }

  // zero this block's output stripe ∩ [len, L)
  const int len = lens_i[b];
  const int begin = t * TILE;
  const int end = begin + TILE;
  const int s0 = (len > begin) ? len : begin;
  const vfloat2 z = {0.f, 0.f};
  for (int i = s0 + (int)threadIdx.x; i < end; i += THREADS) {
    __builtin_nontemporal_store(z, pc2 + i);
    __builtin_nontemporal_store(0.f, w + i);
  }
}

extern "C" void kernel_launch(void* const* d_in, const int* in_sizes, int n_in,
                              void* d_out, int out_size, void* d_ws,
                              size_t ws_size, hipStream_t stream) {
  const float* hist = (const float*)d_in[0];    // [BS, DX, DY]
  const float* x_lims = (const float*)d_in[1];  // [BS, 2]
  const float* y_lims = (const float*)d_in[2];  // [BS, 2]

  float* out = (float*)d_out;
  float* out_pc = out;                          // [BS, L, 2]
  float* out_w = out + (size_t)BS * L * 2;      // [BS, L]
  float* out_lens = out_w + (size_t)BS * L;     // [BS] (as float32)

  int* tile_count = (int*)d_ws;                 // [BS * T_PER_S]
  int* tile_off = tile_count + BS * T_PER_S;    // [BS * T_PER_S]
  int* lens_i = tile_off + BS * T_PER_S;        // [BS]

  htpc_count<<<BS * T_PER_S, THREADS, 0, stream>>>(hist, tile_count);
  htpc_scan<<<BS, 64, 0, stream>>>(tile_count, tile_off, out_lens, lens_i);
  htpc_compact_tail<<<BS * T_PER_S, THREADS, 0, stream>>>(
      hist, x_lims, y_lims, tile_off, lens_i, out_pc, out_w);
}

// Round 4
// 262.294 us; speedup vs baseline: 1.0091x; 1.0091x over previous
//
#include <hip/hip_runtime.h>

// Problem constants (fixed by the reference).
#define BS 64
#define DX 512
#define DY 512
#define L (DX * DY)                 // 262144 bins per sample
#define TILE 4096                   // elements per tile
#define T_PER_S (L / TILE)          // 64 tiles per sample
#define THREADS 256
#define EPT (TILE / THREADS)        // 16 elements per thread

typedef float vfloat2 __attribute__((ext_vector_type(2)));
typedef float vfloat4 __attribute__((ext_vector_type(4)));

// ---------------------------------------------------------------------------
// Phase 1: per-tile nonzero counts. Lane-consecutive float4 loads (ordering
// is irrelevant for counting).
// ---------------------------------------------------------------------------
__global__ __launch_bounds__(THREADS) void htpc_count(
    const float* __restrict__ hist, int* __restrict__ tile_count) {
  const int tile = blockIdx.x;
  const float4* h4 = (const float4*)(hist + (size_t)tile * TILE);

  int cnt = 0;
#pragma unroll
  for (int r = 0; r < EPT / 4; ++r) {
    float4 v = h4[r * THREADS + threadIdx.x];
    cnt += (v.x != 0.f) + (v.y != 0.f) + (v.z != 0.f) + (v.w != 0.f);
  }
  const int lane = threadIdx.x & 63;
  const int wv = threadIdx.x >> 6;
#pragma unroll
  for (int d = 32; d > 0; d >>= 1) cnt += __shfl_down(cnt, d);
  __shared__ int ws[THREADS / 64];
  if (lane == 0) ws[wv] = cnt;
  __syncthreads();
  if (threadIdx.x == 0) {
    int s = 0;
#pragma unroll
    for (int i = 0; i < THREADS / 64; ++i) s += ws[i];
    tile_count[tile] = s;
  }
}

// ---------------------------------------------------------------------------
// Phase 2 (fused scan + compact + tail-zero).
// Each block:
//   a) first wave redundantly exclusive-scans its sample's 64 tile counts
//      (256 B, L2-hot) -> per-tile base offsets + sample length, in LDS;
//   b) reads its tile (per-thread contiguous 16-elem chunk => thread order ==
//      row-major order => stable), block-scans ranks, stages (idx, w) in LDS;
//   c) streams out coalesced nontemporal (x,y) pairs and weights;
//   d) zeroes its output stripe [t*TILE,(t+1)*TILE) ∩ [len, L) with 16B NT
//      stores.
// ---------------------------------------------------------------------------
__global__ __launch_bounds__(THREADS) void htpc_fused(
    const float* __restrict__ hist, const float* __restrict__ x_lims,
    const float* __restrict__ y_lims, const int* __restrict__ tile_count,
    float* __restrict__ out_pc, float* __restrict__ out_w,
    float* __restrict__ out_lens) {
  __shared__ int sidx[TILE];            // 16 KiB
  __shared__ float sw[TILE];            // 16 KiB
  __shared__ int s_off[T_PER_S + 1];    // exclusive offsets + total
  __shared__ int wsum[THREADS / 64];

  const int tile = blockIdx.x;
  const int b = tile >> 6;   // tile / T_PER_S
  const int t = tile & 63;   // tile % T_PER_S
  const size_t gbase = (size_t)tile * TILE + (size_t)threadIdx.x * EPT;
  const float4* h4 = (const float4*)(hist + gbase);

  // issue the tile loads early
  float v[EPT];
#pragma unroll
  for (int i = 0; i < EPT / 4; ++i) {
    float4 a = h4[i];
    v[i * 4 + 0] = a.x;
    v[i * 4 + 1] = a.y;
    v[i * 4 + 2] = a.z;
    v[i * 4 + 3] = a.w;
  }

  // (a) per-sample tile-offset scan, first wave only (wave-uniform branch)
  if (threadIdx.x < 64) {
    const int c = tile_count[b * T_PER_S + threadIdx.x];
    int incl = c;
#pragma unroll
    for (int d = 1; d < 64; d <<= 1) {
      int n = __shfl_up(incl, d);
      if ((int)threadIdx.x >= d) incl += n;
    }
    s_off[threadIdx.x] = incl - c;  // exclusive
    if (threadIdx.x == 63) s_off[T_PER_S] = incl;
  }

  // (b) per-thread counts + block exclusive scan (4 waves)
  int cnt = 0;
#pragma unroll
  for (int i = 0; i < EPT; ++i) cnt += (v[i] != 0.f);

  const int lane = threadIdx.x & 63;
  const int wv = threadIdx.x >> 6;
  int incl = cnt;
#pragma unroll
  for (int d = 1; d < 64; d <<= 1) {
    int n = __shfl_up(incl, d);
    if (lane >= d) incl += n;
  }
  if (lane == 63) wsum[wv] = incl;
  __syncthreads();  // covers s_off and wsum
  int wbase = 0, total = 0;
#pragma unroll
  for (int i = 0; i < THREADS / 64; ++i) {
    int s = wsum[i];
    if (i < wv) wbase += s;
    total += s;
  }
  int r = wbase + (incl - cnt);  // stable exclusive rank within tile

  const int lidx0 = (int)(gbase - (size_t)b * L);  // index within sample
#pragma unroll
  for (int i = 0; i < EPT; ++i) {
    if (v[i] != 0.f) {
      sidx[r] = lidx0 + i;
      sw[r] = v[i];
      ++r;
    }
  }
  __syncthreads();

  // (c) coalesced nontemporal stream-out of the compacted run
  const float xlo = x_lims[b * 2], xhi = x_lims[b * 2 + 1];
  const float ylo = y_lims[b * 2], yhi = y_lims[b * 2 + 1];
  const float cxw = (xhi - xlo) / DX;
  const float cyw = (yhi - ylo) / DY;

  const int off = s_off[t];
  const int len = s_off[T_PER_S];
  vfloat2* pc2 = (vfloat2*)out_pc + (size_t)b * L;  // pair units
  float* w = out_w + (size_t)b * L;

  if (t == 0 && threadIdx.x == 0) out_lens[b] = (float)len;

  for (int k = threadIdx.x; k < total; k += THREADS) {
    const int idx = sidx[k];
    const int ix = idx >> 9;   // idx / DY
    const int iy = idx & 511;  // idx % DY
    vfloat2 p;
    p.x = xlo + cxw * ((float)ix + 0.5f);
    p.y = ylo + cyw * ((float)iy + 0.5f);
    __builtin_nontemporal_store(p, pc2 + (off + k));
    __builtin_nontemporal_store(sw[k], w + (off + k));
  }

  // (d) zero this block's output stripe ∩ [len, L), 16B-vectorized
  const int begin = t * TILE;
  const int end = begin + TILE;
  int s0 = (len > begin) ? len : begin;
  if (s0 < end) {
    // pc: pair units (8 B). Align start to 16 B, then float4 body.
    int a0 = s0;
    if (a0 & 1) {
      if (threadIdx.x == 0) {
        const vfloat2 z2 = {0.f, 0.f};
        __builtin_nontemporal_store(z2, pc2 + a0);
      }
      ++a0;
    }
    {
      vfloat4* p4 = (vfloat4*)(pc2 + a0);
      const int n4 = (end - a0) >> 1;  // pairs per float4 = 2; end,a0 even
      const vfloat4 z4 = {0.f, 0.f, 0.f, 0.f};
      for (int k = threadIdx.x; k < n4; k += THREADS)
        __builtin_nontemporal_store(z4, p4 + k);
    }
    // w: float units (4 B). Scalar head to 16 B boundary, then float4 body.
    const int head = (s0 + 3) & ~3;
    if (threadIdx.x < (head - s0) && (s0 + (int)threadIdx.x) < end)
      __builtin_nontemporal_store(0.f, w + s0 + threadIdx.x);
    if (head < end) {
      vfloat4* w4 = (vfloat4*)(w + head);
      const int n4 = (end - head) >> 2;
      const vfloat4 z4 = {0.f, 0.f, 0.f, 0.f};
      for (int k = threadIdx.x; k < n4; k += THREADS)
        __builtin_nontemporal_store(z4, w4 + k);
    }
  }
}

extern "C" void kernel_launch(void* const* d_in, const int* in_sizes, int n_in,
                              void* d_out, int out_size, void* d_ws,
                              size_t ws_size, hipStream_t stream) {
  const float* hist = (const float*)d_in[0];    // [BS, DX, DY]
  const float* x_lims = (const float*)d_in[1];  // [BS, 2]
  const float* y_lims = (const float*)d_in[2];  // [BS, 2]

  float* out = (float*)d_out;
  float* out_pc = out;                          // [BS, L, 2]
  float* out_w = out + (size_t)BS * L * 2;      // [BS, L]
  float* out_lens = out_w + (size_t)BS * L;     // [BS] (as float32)

  int* tile_count = (int*)d_ws;                 // [BS * T_PER_S]

  htpc_count<<<BS * T_PER_S, THREADS, 0, stream>>>(hist, tile_count);
  htpc_fused<<<BS * T_PER_S, THREADS, 0, stream>>>(
      hist, x_lims, y_lims, tile_count, out_pc, out_w, out_lens);
}